// Round 7
// baseline (480.440 us; speedup 1.0000x reference)
//
#include <hip/hip_runtime.h>
#include <cstddef>

// SPDRectified: out = U clamp(S,eps) U^T for 16384 symmetric 64x64 fp32
// matrices via matrix-sign Newton-Schulz (4 quintic + 3 cubic) on bf16
// matrix cores, 2-word hi/lo split (3-term products, fp32 accum).
//
// Round-7: numerics VERBATIM round-5 (passed, absmax 0.03125) -- the round-6
// 1-term experiment NaN'd via quintic escape (|P'| up to 4 amplifies the
// ~1e-2 1-term noise past the x~1.3 divergence threshold). Structural change
// only: TWO matrices per wave, statically interleaved.
//   r5 fact: 2 hw waves/SIMD gained exactly 0 (phase-locked lockstep -- both
//   waves stall on the same pipe at the same instant). A static interleave
//   cannot lock: each phase is emitted for matrix 0 and matrix 1 in one
//   basic block; the scheduler fills m0's MFMA dependency shadows with m1's
//   VALU and vice versa. 1 wave/SIMD, cap 512 regs; peak ~410.
// Tripwires: WRITE_SIZE must stay 262144 KB (spill = abort); absmax 0.03125.

#define QA 3.4445f
#define QB (-4.7750f)
#define QC 2.0315f

using bf16x8 = __attribute__((ext_vector_type(8))) __bf16;
using f32x16 = __attribute__((ext_vector_type(16))) float;
using u32x4  = __attribute__((ext_vector_type(4))) unsigned int;
using u32x2  = __attribute__((ext_vector_type(2))) unsigned int;

__device__ __forceinline__ bf16x8 asbf(u32x4 v) { return __builtin_bit_cast(bf16x8, v); }

// Pack two f32 -> dword of 2 bf16 (RNE) + dword of 2 bf16 residuals.
// (verbatim round-5, hardware-verified)
__device__ __forceinline__ void split2(float x0, float x1, unsigned& h, unsigned& l) {
    unsigned hh, ll;
    asm("v_cvt_pk_bf16_f32 %0, %1, %2" : "=v"(hh) : "v"(x0), "v"(x1));
    const float e0 = x0 - __uint_as_float(hh << 16);
    const float e1 = x1 - __uint_as_float(hh & 0xFFFF0000u);
    asm("v_cvt_pk_bf16_f32 %0, %1, %2" : "=v"(ll) : "v"(e0), "v"(e1));
    h = hh; l = ll;
}

#define MFMA_(A, B, C) __builtin_amdgcn_mfma_f32_32x32x16_bf16(asbf(A), asbf(B), C, 0, 0, 0)

// 3-term compensated 64x64 product: acc = Ah.Bh + Ah.Bl + Al.Bh (fp32 accum).
// acc[0..3] = tiles (0,0),(0,1),(1,0),(1,1). First MFMAs start from the
// shared zero vector Z0 (D and C are separate fields -> no acc init).
__device__ __forceinline__ void mm12(const u32x4 (&Ah)[2][4], const u32x4 (&Al)[2][4],
                                     const u32x4 (&Bh)[2][4], const u32x4 (&Bl)[2][4],
                                     const f32x16& Z0, f32x16 (&acc)[4]) {
    acc[0] = MFMA_(Ah[0][0], Bh[0][0], Z0);
    acc[1] = MFMA_(Ah[0][0], Bh[1][0], Z0);
    acc[2] = MFMA_(Ah[1][0], Bh[0][0], Z0);
    acc[3] = MFMA_(Ah[1][0], Bh[1][0], Z0);
#pragma unroll
    for (int q = 1; q < 4; ++q) {
        acc[0] = MFMA_(Ah[0][q], Bh[0][q], acc[0]);
        acc[1] = MFMA_(Ah[0][q], Bh[1][q], acc[1]);
        acc[2] = MFMA_(Ah[1][q], Bh[0][q], acc[2]);
        acc[3] = MFMA_(Ah[1][q], Bh[1][q], acc[3]);
    }
#pragma unroll
    for (int q = 0; q < 4; ++q) {
        acc[0] = MFMA_(Ah[0][q], Bl[0][q], acc[0]);
        acc[1] = MFMA_(Ah[0][q], Bl[1][q], acc[1]);
        acc[2] = MFMA_(Ah[1][q], Bl[0][q], acc[2]);
        acc[3] = MFMA_(Ah[1][q], Bl[1][q], acc[3]);
    }
#pragma unroll
    for (int q = 0; q < 4; ++q) {
        acc[0] = MFMA_(Al[0][q], Bh[0][q], acc[0]);
        acc[1] = MFMA_(Al[0][q], Bh[1][q], acc[1]);
        acc[2] = MFMA_(Al[1][q], Bh[0][q], acc[2]);
        acc[3] = MFMA_(Al[1][q], Bh[1][q], acc[3]);
    }
}

// C-layout acc tile (I,J) -> hi/lo A-frags (band J, q=2I+p). Verbatim r5.
__device__ __forceinline__ void conv_tile(const f32x16& cc,
                                          u32x4& fh0, u32x4& fl0,
                                          u32x4& fh1, u32x4& fl1) {
#pragma unroll
    for (int p = 0; p < 2; ++p) {
        unsigned ah0, ah1, bh0, bh1, al0, al1, bl0, bl1;
        split2(cc[8*p+0], cc[8*p+1], ah0, al0);
        split2(cc[8*p+2], cc[8*p+3], ah1, al1);
        split2(cc[8*p+4], cc[8*p+5], bh0, bl0);
        split2(cc[8*p+6], cc[8*p+7], bh1, bl1);
        const u32x2 s0 = __builtin_amdgcn_permlane32_swap(ah0, bh0, false, false);
        const u32x2 s1 = __builtin_amdgcn_permlane32_swap(ah1, bh1, false, false);
        const u32x2 t0 = __builtin_amdgcn_permlane32_swap(al0, bl0, false, false);
        const u32x2 t1 = __builtin_amdgcn_permlane32_swap(al1, bl1, false, false);
        const u32x4 fh = {s0[0], s1[0], s0[1], s1[1]};
        const u32x4 fl = {t0[0], t1[0], t0[1], t1[1]};
        if (p == 0) { fh0 = fh; fl0 = fl; } else { fh1 = fh; fl1 = fl; }
    }
}
// all 4 tiles -> frag set [band][q]
__device__ __forceinline__ void conv4(const f32x16 (&cc)[4],
                                      u32x4 (&FH)[2][4], u32x4 (&FL)[2][4]) {
    conv_tile(cc[0], FH[0][0], FL[0][0], FH[0][1], FL[0][1]);
    conv_tile(cc[1], FH[1][0], FL[1][0], FH[1][1], FL[1][1]);
    conv_tile(cc[2], FH[0][2], FL[0][2], FH[0][3], FL[0][3]);
    conv_tile(cc[3], FH[1][2], FL[1][2], FH[1][3], FL[1][3]);
}

// Inverse of conv_tile (permlane32_swap is an involution): recover Z from its
// frags and combine in place t = QB*Z + QC*t (+QA on diag). Verbatim r5.
__device__ __forceinline__ void recomb_tile(f32x16& t,
                                            const u32x4& gh0, const u32x4& gl0,
                                            const u32x4& gh1, const u32x4& gl1,
                                            bool diag, int hi, int c) {
#pragma unroll
    for (int p = 0; p < 2; ++p) {
        const u32x4 gh = p ? gh1 : gh0;
        const u32x4 gl = p ? gl1 : gl0;
        const u32x2 rh0 = __builtin_amdgcn_permlane32_swap(gh[0], gh[2], false, false);
        const u32x2 rh1 = __builtin_amdgcn_permlane32_swap(gh[1], gh[3], false, false);
        const u32x2 rl0 = __builtin_amdgcn_permlane32_swap(gl[0], gl[2], false, false);
        const u32x2 rl1 = __builtin_amdgcn_permlane32_swap(gl[1], gl[3], false, false);
        const unsigned hdw[4] = {rh0[0], rh1[0], rh0[1], rh1[1]};
        const unsigned ldw[4] = {rl0[0], rl1[0], rl0[1], rl1[1]};
#pragma unroll
        for (int k = 0; k < 4; ++k) {
            const float zlo = __uint_as_float(hdw[k] << 16)
                            + __uint_as_float(ldw[k] << 16);
            const float zhi = __uint_as_float(hdw[k] & 0xFFFF0000u)
                            + __uint_as_float(ldw[k] & 0xFFFF0000u);
            const int r0 = 8*p + 2*k, r1 = r0 + 1;
            float w0 = QB * zlo + QC * t[r0];
            float w1 = QB * zhi + QC * t[r1];
            if (diag) {
                if (((r0 & 3) + 8*(r0 >> 2) + 4*hi) == c) w0 += QA;
                if (((r1 & 3) + 8*(r1 >> 2) + 4*hi) == c) w1 += QA;
            }
            t[r0] = w0; t[r1] = w1;
        }
    }
}
__device__ __forceinline__ void recomb4(f32x16 (&t)[4],
                                        const u32x4 (&GH)[2][4], const u32x4 (&GL)[2][4],
                                        int hi, int c) {
    recomb_tile(t[0], GH[0][0], GL[0][0], GH[0][1], GL[0][1], true,  hi, c);
    recomb_tile(t[1], GH[1][0], GL[1][0], GH[1][1], GL[1][1], false, hi, c);
    recomb_tile(t[2], GH[0][2], GL[0][2], GH[0][3], GL[0][3], false, hi, c);
    recomb_tile(t[3], GH[1][2], GL[1][2], GH[1][3], GL[1][3], true,  hi, c);
}

// final store: out = hsc*(Y0 + C), Y0 reconstructed hi+lo. Verbatim r5 FINTILE.
__device__ __forceinline__ void fin_store(float* __restrict__ Og,
                                          const f32x16 (&ca)[4],
                                          const u32x4 (&Ph)[2][4],
                                          const u32x4 (&Pl)[2][4],
                                          float hsc, int hi, int c) {
#define FINTILE(I, J, CC)                                                       \
    {                                                                           \
        const u32x2 sA0 = __builtin_amdgcn_permlane32_swap(Ph[J][2*I][0],  Ph[J][2*I][2],  false, false); \
        const u32x2 sA1 = __builtin_amdgcn_permlane32_swap(Ph[J][2*I][1],  Ph[J][2*I][3],  false, false); \
        const u32x2 sB0 = __builtin_amdgcn_permlane32_swap(Ph[J][2*I+1][0], Ph[J][2*I+1][2], false, false); \
        const u32x2 sB1 = __builtin_amdgcn_permlane32_swap(Ph[J][2*I+1][1], Ph[J][2*I+1][3], false, false); \
        const u32x2 uA0 = __builtin_amdgcn_permlane32_swap(Pl[J][2*I][0],  Pl[J][2*I][2],  false, false); \
        const u32x2 uA1 = __builtin_amdgcn_permlane32_swap(Pl[J][2*I][1],  Pl[J][2*I][3],  false, false); \
        const u32x2 uB0 = __builtin_amdgcn_permlane32_swap(Pl[J][2*I+1][0], Pl[J][2*I+1][2], false, false); \
        const u32x2 uB1 = __builtin_amdgcn_permlane32_swap(Pl[J][2*I+1][1], Pl[J][2*I+1][3], false, false); \
        _Pragma("unroll")                                                       \
        for (int mq = 0; mq < 4; ++mq) {                                        \
            const int sel = mq & 1;                                             \
            const unsigned hd0 = (mq >> 1) ? sB0[sel] : sA0[sel];               \
            const unsigned hd1 = (mq >> 1) ? sB1[sel] : sA1[sel];               \
            const unsigned ld0 = (mq >> 1) ? uB0[sel] : uA0[sel];               \
            const unsigned ld1 = (mq >> 1) ? uB1[sel] : uA1[sel];               \
            _Pragma("unroll")                                                   \
            for (int j = 0; j < 4; ++j) {                                       \
                const unsigned hd = (j >> 1) ? hd1 : hd0;                       \
                const unsigned ld = (j >> 1) ? ld1 : ld0;                       \
                const float fh = __uint_as_float((j & 1) ? (hd & 0xFFFF0000u) : (hd << 16)); \
                const float fl = __uint_as_float((j & 1) ? (ld & 0xFFFF0000u) : (ld << 16)); \
                const float o  = hsc * ((fh + fl) + CC[4*mq + j]);              \
                Og[(32*(I) + 8*mq + 4*hi + j) * 64 + 32*(J) + c] = o;           \
            }                                                                   \
        }                                                                       \
    }
    FINTILE(0, 0, ca[0])
    FINTILE(0, 1, ca[1])
    FINTILE(1, 0, ca[2])
    FINTILE(1, 1, ca[3])
#undef FINTILE
}

__global__ __launch_bounds__(64, 1)
void spd_rectified_kernel(const float* __restrict__ Xg_all,
                          float* __restrict__ out_all) {
    // Y0 hi/lo parking for both matrices: lane-private 16B slots, 32 KB.
    __shared__ u32x4 park[2][16][64];

    const int lane = threadIdx.x;       // 64 threads = 1 wave, 2 matrices
    const int c    = lane & 31;
    const int hi   = lane >> 5;

    const size_t base = (size_t)blockIdx.x * 8192;   // 2 matrices per block

    const f32x16 Z0v = {};
    u32x4 Yh[2][2][4], Yl[2][2][4], Gh[2][2][4], Gl[2][2][4];
    float alpha[2];

    // ---- init both matrices: load X, Frobenius, split Y0, park ----
#pragma unroll
    for (int m = 0; m < 2; ++m) {
        const float* __restrict__ Xg = Xg_all + base + (size_t)m * 4096;
        float4 xv[2][4][2];
        float ss = 0.f;
#pragma unroll
        for (int b = 0; b < 2; ++b) {
            const float* xr = Xg + (32*b + c) * 64 + 8*hi;
#pragma unroll
            for (int q = 0; q < 4; ++q) {
                const float4 f0 = *reinterpret_cast<const float4*>(xr + 16*q);
                const float4 f1 = *reinterpret_cast<const float4*>(xr + 16*q + 4);
                xv[b][q][0] = f0; xv[b][q][1] = f1;
                ss += f0.x*f0.x + f0.y*f0.y + f0.z*f0.z + f0.w*f0.w;
                ss += f1.x*f1.x + f1.y*f1.y + f1.z*f1.z + f1.w*f1.w;
            }
        }
#pragma unroll
        for (int off = 32; off; off >>= 1) ss += __shfl_xor(ss, off, 64);
        const float ainv = rsqrtf(ss + 1e-30f);
        alpha[m] = ss * ainv;           // sqrt(ss)
#pragma unroll
        for (int b = 0; b < 2; ++b)
#pragma unroll
            for (int q = 0; q < 4; ++q) {
                const float4 f0 = xv[b][q][0], f1 = xv[b][q][1];
                unsigned h0, l0, h1, l1, h2, l2, h3, l3;
                split2(f0.x*ainv, f0.y*ainv, h0, l0);
                split2(f0.z*ainv, f0.w*ainv, h1, l1);
                split2(f1.x*ainv, f1.y*ainv, h2, l2);
                split2(f1.z*ainv, f1.w*ainv, h3, l3);
                Yh[m][b][q] = u32x4{h0, h1, h2, h3};
                Yl[m][b][q] = u32x4{l0, l1, l2, l3};
                park[m][b*4 + q][lane]     = Yh[m][b][q];
                park[m][8 + b*4 + q][lane] = Yl[m][b][q];
            }
    }

    // ---- 4 quintic iterations: Y <- Y*(QA*I + QB*Y^2 + QC*Y^4) ----
#pragma unroll 1
    for (int it = 0; it < 4; ++it) {
        f32x16 za[2][4], ta[2][4];
#pragma unroll
        for (int m = 0; m < 2; ++m)                      // Z = Y^2
            mm12(Yh[m], Yl[m], Yh[m], Yl[m], Z0v, za[m]);
#pragma unroll
        for (int m = 0; m < 2; ++m)                      // Z frags; z accs die
            conv4(za[m], Gh[m], Gl[m]);
#pragma unroll
        for (int m = 0; m < 2; ++m)                      // T = Z^2
            mm12(Gh[m], Gl[m], Gh[m], Gl[m], Z0v, ta[m]);
#pragma unroll
        for (int m = 0; m < 2; ++m)                      // W = QA*I+QB*Z+QC*T
            recomb4(ta[m], Gh[m], Gl[m], hi, c);
#pragma unroll
        for (int m = 0; m < 2; ++m)                      // W frags
            conv4(ta[m], Gh[m], Gl[m]);
#pragma unroll
        for (int m = 0; m < 2; ++m)                      // Ynew = Y*W
            mm12(Yh[m], Yl[m], Gh[m], Gl[m], Z0v, za[m]);
#pragma unroll
        for (int m = 0; m < 2; ++m)
            conv4(za[m], Yh[m], Yl[m]);
    }

    // ---- 3 cubic iterations: Y <- Y*(1.5I - 0.5*Y^2) ----
#pragma unroll 1
    for (int it = 0; it < 3; ++it) {
        f32x16 za[2][4], ya[2][4];
#pragma unroll
        for (int m = 0; m < 2; ++m)                      // Z = Y^2
            mm12(Yh[m], Yl[m], Yh[m], Yl[m], Z0v, za[m]);
#pragma unroll
        for (int m = 0; m < 2; ++m) {                    // W = 1.5I - 0.5Z
#pragma unroll
            for (int r = 0; r < 16; ++r) {
                const int rwc = (r & 3) + 8*(r >> 2) + 4*hi;
                za[m][0][r] = -0.5f*za[m][0][r] + ((rwc == c) ? 1.5f : 0.f);
                za[m][1][r] = -0.5f*za[m][1][r];
                za[m][2][r] = -0.5f*za[m][2][r];
                za[m][3][r] = -0.5f*za[m][3][r] + ((rwc == c) ? 1.5f : 0.f);
            }
        }
#pragma unroll
        for (int m = 0; m < 2; ++m)                      // W frags
            conv4(za[m], Gh[m], Gl[m]);
#pragma unroll
        for (int m = 0; m < 2; ++m)                      // Ynew = Y*W
            mm12(Yh[m], Yl[m], Gh[m], Gl[m], Z0v, ya[m]);
#pragma unroll
        for (int m = 0; m < 2; ++m)
            conv4(ya[m], Yh[m], Yl[m]);
    }

    // ---- final: out = 0.5*alpha*(Y0 + Y0*S), S = Y ----
    u32x4 Ph[2][2][4], Pl[2][2][4];
    f32x16 ca[2][4];
#pragma unroll
    for (int m = 0; m < 2; ++m) {
#pragma unroll
        for (int b = 0; b < 2; ++b)
#pragma unroll
            for (int q = 0; q < 4; ++q) {
                Ph[m][b][q] = park[m][b*4 + q][lane];
                Pl[m][b][q] = park[m][8 + b*4 + q][lane];
            }
        mm12(Ph[m], Pl[m], Yh[m], Yl[m], Z0v, ca[m]);    // C = Y0*S
    }
#pragma unroll
    for (int m = 0; m < 2; ++m) {
        float* __restrict__ Og = out_all + base + (size_t)m * 4096;
        fin_store(Og, ca[m], Ph[m], Pl[m], 0.5f * alpha[m], hi, c);
    }
}

extern "C" void kernel_launch(void* const* d_in, const int* in_sizes, int n_in,
                              void* d_out, int out_size, void* d_ws, size_t ws_size,
                              hipStream_t stream) {
    const float* x = (const float*)d_in[0];
    float* out = (float*)d_out;
    const int nmat = in_sizes[0] >> 12;   // / 4096
    spd_rectified_kernel<<<nmat >> 1, 64, 0, stream>>>(x, out);
}

// Round 9
// 377.820 us; speedup vs baseline: 1.2716x; 1.2716x over previous
//
#include <hip/hip_runtime.h>
#include <cstddef>

// SPDRectified: out = U clamp(S,eps) U^T for 16384 symmetric 64x64 fp32
// matrices via matrix-sign Newton-Schulz, one wave per matrix, bf16 matrix
// cores, 2-word hi/lo split (3-term products, fp32 accum) -- r5 numerics.
//
// Round-9 (r6/r8 1-term experiments both escaped the quintic trap; 3-term
// is mandatory in the quintic phase):
//  1. SPECTRAL normalization: lam = ||X^6 1||/||X^5 1|| (6 in-register
//     matvecs), nu = min(1.3*lam, ||X||_F). lam <= lamax always, so top
//     |eig(Y0)| <= ~1.0 typical (trap edge 1.2637, P monotone there ->
//     deterministically trapped). Recovers the 4x Frobenius waste ->
//     3 quintics suffice (slope 3.44^3*1.5^3*3.2 ~ 446 vs r5's 476).
//  2. beta-scaled iterate (beta = QC^(1/4)): Z-accs = sqrt(QC)*Z, so the
//     T-chain seeded with C0 = QA*I + (QB/sqrt(QC))*Zaccs (in-place FMA)
//     directly yields W-accs -- recomb (inverse permlanes) deleted, only
//     one f32x16[4] acc array live. Exact algebra, no precision change.
//  3. Final folded: M = (I+S)/2 from last cubic's accs; out = nu*Y0*M
//     written straight from accs (FINTILE reconstruction deleted).
// Tripwires: WRITE_SIZE == 262144 KB; absmax ~0.033 expected (<0.119);
// 0.12-0.3 => restore 4th quintic; >>1/NaN => revert to Frobenius norm.

#define QA 3.4445f
#define QB (-4.7750f)
#define QC 2.0315f
#define BETA    1.1938624f      // QC^(1/4)
#define C0COEF  (-3.3501551f)   // QB / sqrt(QC)
#define CWCOEF  (-0.3508013f)   // -0.5 / sqrt(QC)
#define CMCOEF  (0.4188090f)    // 0.5 / BETA
#define INVBETA (0.8376177f)    // 1 / BETA

using bf16x8 = __attribute__((ext_vector_type(8))) __bf16;
using f32x16 = __attribute__((ext_vector_type(16))) float;
using u32x4  = __attribute__((ext_vector_type(4))) unsigned int;
using u32x2  = __attribute__((ext_vector_type(2))) unsigned int;

__device__ __forceinline__ bf16x8 asbf(u32x4 v) { return __builtin_bit_cast(bf16x8, v); }

// Pack two f32 -> dword of 2 bf16 (RNE) + dword of 2 bf16 residuals.
__device__ __forceinline__ void split2(float x0, float x1, unsigned& h, unsigned& l) {
    unsigned hh, ll;
    asm("v_cvt_pk_bf16_f32 %0, %1, %2" : "=v"(hh) : "v"(x0), "v"(x1));
    const float e0 = x0 - __uint_as_float(hh << 16);
    const float e1 = x1 - __uint_as_float(hh & 0xFFFF0000u);
    asm("v_cvt_pk_bf16_f32 %0, %1, %2" : "=v"(ll) : "v"(e0), "v"(e1));
    h = hh; l = ll;
}

#define MFMA_(A, B, C) __builtin_amdgcn_mfma_f32_32x32x16_bf16(asbf(A), asbf(B), C, 0, 0, 0)

// 3-term product accumulating into pre-initialized acc (C-operand seeding).
__device__ __forceinline__ void mm12c(const u32x4 (&Ah)[2][4], const u32x4 (&Al)[2][4],
                                      const u32x4 (&Bh)[2][4], const u32x4 (&Bl)[2][4],
                                      f32x16 (&acc)[4]) {
    __builtin_amdgcn_s_setprio(1);
#pragma unroll
    for (int q = 0; q < 4; ++q) {
        acc[0] = MFMA_(Ah[0][q], Bh[0][q], acc[0]);
        acc[1] = MFMA_(Ah[0][q], Bh[1][q], acc[1]);
        acc[2] = MFMA_(Ah[1][q], Bh[0][q], acc[2]);
        acc[3] = MFMA_(Ah[1][q], Bh[1][q], acc[3]);
    }
#pragma unroll
    for (int q = 0; q < 4; ++q) {
        acc[0] = MFMA_(Ah[0][q], Bl[0][q], acc[0]);
        acc[1] = MFMA_(Ah[0][q], Bl[1][q], acc[1]);
        acc[2] = MFMA_(Ah[1][q], Bl[0][q], acc[2]);
        acc[3] = MFMA_(Ah[1][q], Bl[1][q], acc[3]);
    }
#pragma unroll
    for (int q = 0; q < 4; ++q) {
        acc[0] = MFMA_(Al[0][q], Bh[0][q], acc[0]);
        acc[1] = MFMA_(Al[0][q], Bh[1][q], acc[1]);
        acc[2] = MFMA_(Al[1][q], Bh[0][q], acc[2]);
        acc[3] = MFMA_(Al[1][q], Bh[1][q], acc[3]);
    }
    __builtin_amdgcn_s_setprio(0);
}
// 3-term product from zero (shared zero vector as first C-operand).
__device__ __forceinline__ void mm12z(const u32x4 (&Ah)[2][4], const u32x4 (&Al)[2][4],
                                      const u32x4 (&Bh)[2][4], const u32x4 (&Bl)[2][4],
                                      const f32x16& Z0, f32x16 (&acc)[4]) {
    __builtin_amdgcn_s_setprio(1);
    acc[0] = MFMA_(Ah[0][0], Bh[0][0], Z0);
    acc[1] = MFMA_(Ah[0][0], Bh[1][0], Z0);
    acc[2] = MFMA_(Ah[1][0], Bh[0][0], Z0);
    acc[3] = MFMA_(Ah[1][0], Bh[1][0], Z0);
#pragma unroll
    for (int q = 1; q < 4; ++q) {
        acc[0] = MFMA_(Ah[0][q], Bh[0][q], acc[0]);
        acc[1] = MFMA_(Ah[0][q], Bh[1][q], acc[1]);
        acc[2] = MFMA_(Ah[1][q], Bh[0][q], acc[2]);
        acc[3] = MFMA_(Ah[1][q], Bh[1][q], acc[3]);
    }
    __builtin_amdgcn_s_setprio(0);
    mm12c(Ah, Al, Bh, Bl, acc);   // adds nothing for q-loop1? no: see note
}

// NOTE: mm12z must not re-add the Ah*Bh term; implement explicitly instead.
__device__ __forceinline__ void mm12(const u32x4 (&Ah)[2][4], const u32x4 (&Al)[2][4],
                                     const u32x4 (&Bh)[2][4], const u32x4 (&Bl)[2][4],
                                     const f32x16& Z0, f32x16 (&acc)[4]) {
    __builtin_amdgcn_s_setprio(1);
    acc[0] = MFMA_(Ah[0][0], Bh[0][0], Z0);
    acc[1] = MFMA_(Ah[0][0], Bh[1][0], Z0);
    acc[2] = MFMA_(Ah[1][0], Bh[0][0], Z0);
    acc[3] = MFMA_(Ah[1][0], Bh[1][0], Z0);
#pragma unroll
    for (int q = 1; q < 4; ++q) {
        acc[0] = MFMA_(Ah[0][q], Bh[0][q], acc[0]);
        acc[1] = MFMA_(Ah[0][q], Bh[1][q], acc[1]);
        acc[2] = MFMA_(Ah[1][q], Bh[0][q], acc[2]);
        acc[3] = MFMA_(Ah[1][q], Bh[1][q], acc[3]);
    }
#pragma unroll
    for (int q = 0; q < 4; ++q) {
        acc[0] = MFMA_(Ah[0][q], Bl[0][q], acc[0]);
        acc[1] = MFMA_(Ah[0][q], Bl[1][q], acc[1]);
        acc[2] = MFMA_(Ah[1][q], Bl[0][q], acc[2]);
        acc[3] = MFMA_(Ah[1][q], Bl[1][q], acc[3]);
    }
#pragma unroll
    for (int q = 0; q < 4; ++q) {
        acc[0] = MFMA_(Al[0][q], Bh[0][q], acc[0]);
        acc[1] = MFMA_(Al[0][q], Bh[1][q], acc[1]);
        acc[2] = MFMA_(Al[1][q], Bh[0][q], acc[2]);
        acc[3] = MFMA_(Al[1][q], Bh[1][q], acc[3]);
    }
    __builtin_amdgcn_s_setprio(0);
}

// C-layout acc tile (I,J) -> hi/lo A-frags (band J, q=2I+p). Verified r4-r7.
__device__ __forceinline__ void conv_tile(const f32x16& cc,
                                          u32x4& fh0, u32x4& fl0,
                                          u32x4& fh1, u32x4& fl1) {
#pragma unroll
    for (int p = 0; p < 2; ++p) {
        unsigned ah0, ah1, bh0, bh1, al0, al1, bl0, bl1;
        split2(cc[8*p+0], cc[8*p+1], ah0, al0);
        split2(cc[8*p+2], cc[8*p+3], ah1, al1);
        split2(cc[8*p+4], cc[8*p+5], bh0, bl0);
        split2(cc[8*p+6], cc[8*p+7], bh1, bl1);
        const u32x2 s0 = __builtin_amdgcn_permlane32_swap(ah0, bh0, false, false);
        const u32x2 s1 = __builtin_amdgcn_permlane32_swap(ah1, bh1, false, false);
        const u32x2 t0 = __builtin_amdgcn_permlane32_swap(al0, bl0, false, false);
        const u32x2 t1 = __builtin_amdgcn_permlane32_swap(al1, bl1, false, false);
        const u32x4 fh = {s0[0], s1[0], s0[1], s1[1]};
        const u32x4 fl = {t0[0], t1[0], t0[1], t1[1]};
        if (p == 0) { fh0 = fh; fl0 = fl; } else { fh1 = fh; fl1 = fl; }
    }
}
__device__ __forceinline__ void conv4(const f32x16 (&cc)[4],
                                      u32x4 (&FH)[2][4], u32x4 (&FL)[2][4]) {
    conv_tile(cc[0], FH[0][0], FL[0][0], FH[0][1], FL[0][1]);
    conv_tile(cc[1], FH[1][0], FL[1][0], FH[1][1], FL[1][1]);
    conv_tile(cc[2], FH[0][2], FL[0][2], FH[0][3], FL[0][3]);
    conv_tile(cc[3], FH[1][2], FL[1][2], FH[1][3], FL[1][3]);
}

__global__ __launch_bounds__(64, 2)
void spd_rectified_kernel(const float* __restrict__ Xg_all,
                          float* __restrict__ out_all) {
    // beta*Y0 hi/lo parking: lane-private 16B slots, conflict-free, 16 KB.
    __shared__ u32x4 park[16][64];

    const int lane = threadIdx.x;       // 64 threads = 1 wave
    const int c    = lane & 31;
    const int hi   = lane >> 5;
    const int dv   = c - 4 * hi;        // diag: (r&3)+8*(r>>2) == dv

    const float* __restrict__ Xg = Xg_all + (size_t)blockIdx.x * 4096;
    float* __restrict__ Og = out_all + (size_t)blockIdx.x * 4096;

    // ---- load X in frag-shaped slices: row 32b+c, k = 16q+8hi+[0,8) ----
    float4 xv[2][4][2];
    float ss = 0.f;
#pragma unroll
    for (int b = 0; b < 2; ++b) {
        const float* xr = Xg + (32*b + c) * 64 + 8*hi;
#pragma unroll
        for (int q = 0; q < 4; ++q) {
            const float4 f0 = *reinterpret_cast<const float4*>(xr + 16*q);
            const float4 f1 = *reinterpret_cast<const float4*>(xr + 16*q + 4);
            xv[b][q][0] = f0; xv[b][q][1] = f1;
            ss += f0.x*f0.x + f0.y*f0.y + f0.z*f0.z + f0.w*f0.w;
            ss += f1.x*f1.x + f1.y*f1.y + f1.z*f1.z + f1.w*f1.w;
        }
    }
#pragma unroll
    for (int off = 32; off; off >>= 1) ss += __shfl_xor(ss, off, 64);
    const float fnorm = sqrtf(ss + 1e-30f);
    const float finv  = 1.0f / fnorm;

    // ---- spectral estimate: 6 power-iteration matvecs, lam = n6/n5 ----
    float v[4][8];
#pragma unroll
    for (int q = 0; q < 4; ++q)
#pragma unroll
        for (int j = 0; j < 8; ++j) v[q][j] = 1.0f;
    float n5 = 1.f, n6 = 1.f;
#pragma unroll
    for (int m = 1; m <= 6; ++m) {
        float y0 = 0.f, y1 = 0.f;
#pragma unroll
        for (int q = 0; q < 4; ++q) {
            const float4 a0 = xv[0][q][0], a1 = xv[0][q][1];
            const float4 b0 = xv[1][q][0], b1 = xv[1][q][1];
            y0 += a0.x*v[q][0] + a0.y*v[q][1] + a0.z*v[q][2] + a0.w*v[q][3]
                + a1.x*v[q][4] + a1.y*v[q][5] + a1.z*v[q][6] + a1.w*v[q][7];
            y1 += b0.x*v[q][0] + b0.y*v[q][1] + b0.z*v[q][2] + b0.w*v[q][3]
                + b1.x*v[q][4] + b1.y*v[q][5] + b1.z*v[q][6] + b1.w*v[q][7];
        }
        y0 += __shfl_xor(y0, 32, 64);
        y1 += __shfl_xor(y1, 32, 64);
        if (m == 3) { y0 *= finv; y1 *= finv; }   // overflow guard
        if (m >= 5) {
            float t = y0*y0 + y1*y1;
#pragma unroll
            for (int off = 16; off; off >>= 1) t += __shfl_xor(t, off, 64);
            if (m == 5) n5 = t; else n6 = t;
        }
        if (m < 6) {
#pragma unroll
            for (int q = 0; q < 4; ++q)
#pragma unroll
                for (int j = 0; j < 8; ++j)
                    v[q][j] = __shfl((q < 2) ? y0 : y1, 16*(q & 1) + 8*hi + j, 64);
        }
    }
    const float rho = sqrtf(n6 / n5);
    float nu = fminf(1.3f * rho, fnorm);
    if (!(nu > 1e-25f)) nu = fnorm;     // NaN/zero backstop -> Frobenius
    const float alpha = nu;
    const float ainvb = (1.0f / nu) * BETA;   // iterate stored as beta*Y

    const f32x16 Z0 = {};

    // ---- Ytil = beta*X/nu as hi/lo frags; park a copy ----
    u32x4 Yh[2][4], Yl[2][4], Gh[2][4], Gl[2][4];
#pragma unroll
    for (int b = 0; b < 2; ++b)
#pragma unroll
        for (int q = 0; q < 4; ++q) {
            const float4 f0 = xv[b][q][0], f1 = xv[b][q][1];
            unsigned h0, l0, h1, l1, h2, l2, h3, l3;
            split2(f0.x*ainvb, f0.y*ainvb, h0, l0);
            split2(f0.z*ainvb, f0.w*ainvb, h1, l1);
            split2(f1.x*ainvb, f1.y*ainvb, h2, l2);
            split2(f1.z*ainvb, f1.w*ainvb, h3, l3);
            Yh[b][q] = u32x4{h0, h1, h2, h3};
            Yl[b][q] = u32x4{l0, l1, l2, l3};
            park[b*4 + q][lane]     = Yh[b][q];
            park[8 + b*4 + q][lane] = Yl[b][q];
        }

    f32x16 za[4];

    // ---- 3 quintic iterations (beta-invariant, C0-seeded T-chain) ----
#pragma unroll 1
    for (int it = 0; it < 3; ++it) {
        mm12(Yh, Yl, Yh, Yl, Z0, za);                // za = beta^2*Y^2 = sqrt(QC)*Z
        conv4(za, Gh, Gl);                           // Z-frags (scaled)
#pragma unroll
        for (int r = 0; r < 16; ++r) {               // C0 = QA*I + (QB/sqrtQC)*za
            const int rwc = (r & 3) + 8*(r >> 2);
            za[0][r] = C0COEF*za[0][r] + ((rwc == dv) ? QA : 0.f);
            za[1][r] = C0COEF*za[1][r];
            za[2][r] = C0COEF*za[2][r];
            za[3][r] = C0COEF*za[3][r] + ((rwc == dv) ? QA : 0.f);
        }
        mm12c(Gh, Gl, Gh, Gl, za);                   // za = W = QA*I+QB*Z+QC*Z^2
        conv4(za, Gh, Gl);                           // W-frags
        mm12(Yh, Yl, Gh, Gl, Z0, za);                // za = beta*(Y*W) = Ytil_new
        conv4(za, Yh, Yl);
    }

    // ---- 3 cubic iterations; last one emits M = (I+S)/2 ----
#pragma unroll 1
    for (int it = 0; it < 3; ++it) {
        mm12(Yh, Yl, Yh, Yl, Z0, za);                // za = sqrt(QC)... = beta^2*Y^2
#pragma unroll
        for (int r = 0; r < 16; ++r) {               // W = 1.5I - 0.5*Y^2
            const int rwc = (r & 3) + 8*(r >> 2);
            za[0][r] = CWCOEF*za[0][r] + ((rwc == dv) ? 1.5f : 0.f);
            za[1][r] = CWCOEF*za[1][r];
            za[2][r] = CWCOEF*za[2][r];
            za[3][r] = CWCOEF*za[3][r] + ((rwc == dv) ? 1.5f : 0.f);
        }
        conv4(za, Gh, Gl);                           // W-frags
        mm12(Yh, Yl, Gh, Gl, Z0, za);                // za = beta*(Y*W)
        if (it == 2) {
#pragma unroll
            for (int r = 0; r < 16; ++r) {           // M = 0.5I + (0.5/beta)*za
                const int rwc = (r & 3) + 8*(r >> 2);
                za[0][r] = CMCOEF*za[0][r] + ((rwc == dv) ? 0.5f : 0.f);
                za[1][r] = CMCOEF*za[1][r];
                za[2][r] = CMCOEF*za[2][r];
                za[3][r] = CMCOEF*za[3][r] + ((rwc == dv) ? 0.5f : 0.f);
            }
        }
        conv4(za, Yh, Yl);                           // iterate / M frags
    }

    // ---- final: out = nu*Y0*M = (nu/beta)*(betaY0)*M ----
    u32x4 Ph[2][4], Pl[2][4];
#pragma unroll
    for (int b = 0; b < 2; ++b)
#pragma unroll
        for (int q = 0; q < 4; ++q) {
            Ph[b][q] = park[b*4 + q][lane];
            Pl[b][q] = park[8 + b*4 + q][lane];
        }
    mm12(Ph, Pl, Yh, Yl, Z0, za);                    // za = beta*Y0*M
    const float hscb = alpha * INVBETA;

#pragma unroll
    for (int t = 0; t < 4; ++t) {
        const int I = t >> 1, J = t & 1;
#pragma unroll
        for (int g = 0; g < 4; ++g)
#pragma unroll
            for (int j = 0; j < 4; ++j)
                Og[(32*I + 8*g + 4*hi + j) * 64 + 32*J + c] = hscb * za[t][4*g + j];
    }
}

extern "C" void kernel_launch(void* const* d_in, const int* in_sizes, int n_in,
                              void* d_out, int out_size, void* d_ws, size_t ws_size,
                              hipStream_t stream) {
    const float* x = (const float*)d_in[0];
    float* out = (float*)d_out;
    const int nmat = in_sizes[0] >> 12;
    spd_rectified_kernel<<<nmat, 64, 0, stream>>>(x, out);
}